// Round 1
// baseline (569.746 us; speedup 1.0000x reference)
//
#include <hip/hip_runtime.h>
#include <cstdint>

typedef __bf16 bf16x8 __attribute__((ext_vector_type(8)));
typedef float f32x4 __attribute__((ext_vector_type(4)));
typedef unsigned short u16;

#define MFMA16(a, b, c) __builtin_amdgcn_mfma_f32_16x16x32_bf16((a), (b), (c), 0, 0, 0)

__device__ __forceinline__ u16 f2bf(float f) {
    union { float f; uint32_t u; } v; v.f = f;
    uint32_t u = v.u;
    u += 0x7FFFu + ((u >> 16) & 1u);   // RNE
    return (u16)(u >> 16);
}
__device__ __forceinline__ float bf2f(u16 h) {
    union { uint32_t u; float f; } v; v.u = ((uint32_t)h) << 16;
    return v.f;
}

// ---------------------------------------------------------------- transpose+cast
// in: fp32 [R][C] row-major  ->  out: bf16 [C][R] row-major
__global__ __launch_bounds__(256) void transpose_cast(const float* __restrict__ in,
                                                      u16* __restrict__ out, int R, int C) {
    __shared__ float tile[32][33];
    int c0 = blockIdx.x * 32, r0 = blockIdx.y * 32;
    int tx = threadIdx.x & 31, ty = threadIdx.x >> 5;
#pragma unroll
    for (int i = ty; i < 32; i += 8)
        tile[i][tx] = in[(size_t)(r0 + i) * C + c0 + tx];
    __syncthreads();
#pragma unroll
    for (int i = ty; i < 32; i += 8)
        out[(size_t)(c0 + i) * R + r0 + tx] = f2bf(tile[tx][i]);
}

// bf16 transpose of the V section of qkv: in [2048][*stride] cols c0..c0+255 -> vT [256][2048] per batch
__global__ __launch_bounds__(256) void transpose_v(const u16* __restrict__ in, u16* __restrict__ out,
                                                   int in_stride) {
    __shared__ u16 tile[32][33];
    int b = blockIdx.z;
    int c0 = blockIdx.x * 32, s0 = blockIdx.y * 32;
    int tx = threadIdx.x & 31, ty = threadIdx.x >> 5;
#pragma unroll
    for (int i = ty; i < 32; i += 8)
        tile[i][tx] = in[(size_t)(b * 2048 + s0 + i) * in_stride + c0 + tx];
    __syncthreads();
#pragma unroll
    for (int i = ty; i < 32; i += 8)
        out[(size_t)b * 256 * 2048 + (size_t)(c0 + i) * 2048 + s0 + tx] = tile[tx][i];
}

// ---------------------------------------------------------------- LayerNorm -> bf16
__global__ __launch_bounds__(256) void ln_kernel(const float* __restrict__ x,
                                                 const float* __restrict__ w,
                                                 const float* __restrict__ bb,
                                                 u16* __restrict__ normed) {
    int row = blockIdx.x;
    int tid = threadIdx.x;
    float4 v = ((const float4*)(x + (size_t)row * 1024))[tid];
    float s = v.x + v.y + v.z + v.w;
    float s2 = v.x * v.x + v.y * v.y + v.z * v.z + v.w * v.w;
#pragma unroll
    for (int off = 1; off < 64; off <<= 1) {
        s += __shfl_xor(s, off);
        s2 += __shfl_xor(s2, off);
    }
    __shared__ float rs[4], rs2[4];
    int wv = tid >> 6;
    if ((tid & 63) == 0) { rs[wv] = s; rs2[wv] = s2; }
    __syncthreads();
    s = rs[0] + rs[1] + rs[2] + rs[3];
    s2 = rs2[0] + rs2[1] + rs2[2] + rs2[3];
    float mu = s * (1.0f / 1024.0f);
    float var = s2 * (1.0f / 1024.0f) - mu * mu;
    float inv = rsqrtf(var + 1e-5f);
    float4 wv4 = ((const float4*)w)[tid];
    float4 bv4 = ((const float4*)bb)[tid];
    ushort4 o;
    o.x = f2bf((v.x - mu) * inv * wv4.x + bv4.x);
    o.y = f2bf((v.y - mu) * inv * wv4.y + bv4.y);
    o.z = f2bf((v.z - mu) * inv * wv4.z + bv4.z);
    o.w = f2bf((v.w - mu) * inv * wv4.w + bv4.w);
    *(ushort4*)(normed + (size_t)row * 1024 + tid * 4) = o;
}

// ---------------------------------------------------------------- GEMM (A[M][K] bf16 x Bt[N][K] bf16)
// mode 0: C=bf16 plain; mode 1: C=f32 plain; mode 2: C=bf16 = silu(aux)*acc
#define BM 128
#define BN 128
#define BKC 32
#define LDP 40

__global__ __launch_bounds__(256) void gemm_bt(const u16* __restrict__ A, const u16* __restrict__ Bt,
                                               void* __restrict__ Cv, const u16* __restrict__ aux,
                                               int N, int K, int mode) {
    __shared__ u16 As[BM][LDP];
    __shared__ u16 Bs[BN][LDP];
    const int tid = threadIdx.x;
    const int lane = tid & 63;
    const int wv = tid >> 6;
    const int row0 = blockIdx.x * BM;
    const int col0 = blockIdx.y * BN;
    const int wr = (wv >> 1) * 64;
    const int wc = (wv & 1) * 64;
    const int fr = lane & 15;
    const int fg = lane >> 4;

    f32x4 acc[4][4];
#pragma unroll
    for (int i = 0; i < 4; ++i)
#pragma unroll
        for (int j = 0; j < 4; ++j)
            acc[i][j] = (f32x4){0.f, 0.f, 0.f, 0.f};

    for (int k0 = 0; k0 < K; k0 += BKC) {
        __syncthreads();
#pragma unroll
        for (int p = 0; p < 2; ++p) {
            int idx = p * 256 + tid;
            int r = idx >> 2, ch = idx & 3;
            *(uint4*)(&As[r][ch * 8]) = *(const uint4*)(&A[(size_t)(row0 + r) * K + k0 + ch * 8]);
            *(uint4*)(&Bs[r][ch * 8]) = *(const uint4*)(&Bt[(size_t)(col0 + r) * K + k0 + ch * 8]);
        }
        __syncthreads();
        bf16x8 af[4], bfr[4];
#pragma unroll
        for (int i = 0; i < 4; ++i) af[i] = *(const bf16x8*)(&As[wr + i * 16 + fr][fg * 8]);
#pragma unroll
        for (int j = 0; j < 4; ++j) bfr[j] = *(const bf16x8*)(&Bs[wc + j * 16 + fr][fg * 8]);
#pragma unroll
        for (int i = 0; i < 4; ++i)
#pragma unroll
            for (int j = 0; j < 4; ++j)
                acc[i][j] = MFMA16(af[i], bfr[j], acc[i][j]);
    }

    if (mode == 0) {
        u16* C = (u16*)Cv;
#pragma unroll
        for (int i = 0; i < 4; ++i)
#pragma unroll
            for (int j = 0; j < 4; ++j)
#pragma unroll
                for (int r = 0; r < 4; ++r) {
                    int row = row0 + wr + i * 16 + fg * 4 + r;
                    int col = col0 + wc + j * 16 + fr;
                    C[(size_t)row * N + col] = f2bf(acc[i][j][r]);
                }
    } else if (mode == 1) {
        float* C = (float*)Cv;
#pragma unroll
        for (int i = 0; i < 4; ++i)
#pragma unroll
            for (int j = 0; j < 4; ++j)
#pragma unroll
                for (int r = 0; r < 4; ++r) {
                    int row = row0 + wr + i * 16 + fg * 4 + r;
                    int col = col0 + wc + j * 16 + fr;
                    C[(size_t)row * N + col] = acc[i][j][r];
                }
    } else {
        u16* C = (u16*)Cv;
#pragma unroll
        for (int i = 0; i < 4; ++i)
#pragma unroll
            for (int j = 0; j < 4; ++j)
#pragma unroll
                for (int r = 0; r < 4; ++r) {
                    int row = row0 + wr + i * 16 + fg * 4 + r;
                    int col = col0 + wc + j * 16 + fr;
                    float g = bf2f(aux[(size_t)row * N + col]);
                    float sg = g / (1.0f + __expf(-g));
                    C[(size_t)row * N + col] = f2bf(sg * acc[i][j][r]);
                }
    }
}

// ---------------------------------------------------------------- flash attention
// qkv bf16 [4096][1536] (q cols 0..1023 h-major, k cols 1024..1279 kh-major, v cols 1280..1535)
// Vt bf16 [2][4][64][2048]; out bf16 [4096][1024]
__global__ __launch_bounds__(256) void attn_kernel(const u16* __restrict__ qkv,
                                                   const u16* __restrict__ Vt,
                                                   u16* __restrict__ Ob) {
    __shared__ u16 Pl[4][16][LDP];
    const int lane = threadIdx.x & 63;
    const int w = threadIdx.x >> 6;
    const int wid = blockIdx.x * 4 + w;
    const int qt = wid & 127;
    const int h = (wid >> 7) & 15;
    const int b = wid >> 11;
    const int kh = h >> 2;
    const int fr = lane & 15, fg = lane >> 4;
    const int S = 2048, QS = 1536;

    const u16* qbase = qkv + (size_t)(b * S + qt * 16 + fr) * QS + h * 64 + fg * 8;
    bf16x8 aq0 = *(const bf16x8*)(qbase);
    bf16x8 aq1 = *(const bf16x8*)(qbase + 32);

    f32x4 o[4];
    float mr[4], ls[4];
#pragma unroll
    for (int nb = 0; nb < 4; ++nb) o[nb] = (f32x4){0.f, 0.f, 0.f, 0.f};
#pragma unroll
    for (int r = 0; r < 4; ++r) { mr[r] = -1e30f; ls[r] = 0.f; }

    const int ntiles = (qt >> 1) + 1;
    for (int t = 0; t < ntiles; ++t) {
        const int kv0 = t * 32;
        const u16* kb = qkv + (size_t)(b * S + kv0) * QS + 1024 + kh * 64 + fg * 8;
        bf16x8 k00 = *(const bf16x8*)(kb + (size_t)fr * QS);
        bf16x8 k01 = *(const bf16x8*)(kb + (size_t)fr * QS + 32);
        bf16x8 k10 = *(const bf16x8*)(kb + (size_t)(fr + 16) * QS);
        bf16x8 k11 = *(const bf16x8*)(kb + (size_t)(fr + 16) * QS + 32);
        f32x4 s0 = (f32x4){0.f, 0.f, 0.f, 0.f};
        f32x4 s1 = (f32x4){0.f, 0.f, 0.f, 0.f};
        s0 = MFMA16(aq0, k00, s0);
        s0 = MFMA16(aq1, k01, s0);
        s1 = MFMA16(aq0, k10, s1);
        s1 = MFMA16(aq1, k11, s1);

        float al[4];
#pragma unroll
        for (int r = 0; r < 4; ++r) {
            int row = qt * 16 + fg * 4 + r;
            float x0 = (kv0 + fr <= row) ? s0[r] * 0.125f : -1e30f;
            float x1 = (kv0 + 16 + fr <= row) ? s1[r] * 0.125f : -1e30f;
            float m = fmaxf(x0, x1);
#pragma unroll
            for (int off = 1; off < 16; off <<= 1) m = fmaxf(m, __shfl_xor(m, off));
            float nm = fmaxf(mr[r], m);
            al[r] = __expf(mr[r] - nm);
            mr[r] = nm;
            float p0 = __expf(x0 - nm);
            float p1 = __expf(x1 - nm);
            Pl[w][fg * 4 + r][fr] = f2bf(p0);
            Pl[w][fg * 4 + r][16 + fr] = f2bf(p1);
            float sum = p0 + p1;
#pragma unroll
            for (int off = 1; off < 16; off <<= 1) sum += __shfl_xor(sum, off);
            ls[r] = ls[r] * al[r] + sum;
        }
#pragma unroll
        for (int nb = 0; nb < 4; ++nb)
#pragma unroll
            for (int r = 0; r < 4; ++r)
                o[nb][r] = o[nb][r] * al[r];

        asm volatile("s_waitcnt lgkmcnt(0)" ::: "memory");
        bf16x8 pa = *(const bf16x8*)(&Pl[w][fr][fg * 8]);
        const u16* vb = Vt + ((size_t)(b * 4 + kh) * 64) * 2048 + kv0 + fg * 8;
#pragma unroll
        for (int nb = 0; nb < 4; ++nb) {
            bf16x8 vf = *(const bf16x8*)(vb + (size_t)(nb * 16 + fr) * 2048);
            o[nb] = MFMA16(pa, vf, o[nb]);
        }
    }

    float inv[4];
#pragma unroll
    for (int r = 0; r < 4; ++r) inv[r] = 1.0f / ls[r];
    u16* ob = Ob + (size_t)(b * S + qt * 16) * 1024 + h * 64;
#pragma unroll
    for (int nb = 0; nb < 4; ++nb)
#pragma unroll
        for (int r = 0; r < 4; ++r)
            ob[(size_t)(fg * 4 + r) * 1024 + nb * 16 + fr] = f2bf(o[nb][r] * inv[r]);
}

// ---------------------------------------------------------------- final residual add
__global__ __launch_bounds__(256) void add3_kernel(const float* __restrict__ x,
                                                   const float* __restrict__ p1,
                                                   const float* __restrict__ p2,
                                                   float* __restrict__ out) {
    size_t i = (size_t)blockIdx.x * 256 + threadIdx.x;
    float4 a = ((const float4*)x)[i];
    float4 b = ((const float4*)p1)[i];
    float4 c = ((const float4*)p2)[i];
    float4 o;
    o.x = a.x + b.x + c.x;
    o.y = a.y + b.y + c.y;
    o.z = a.z + b.z + c.z;
    o.w = a.w + b.w + c.w;
    ((float4*)out)[i] = o;
}

// ---------------------------------------------------------------- launch
extern "C" void kernel_launch(void* const* d_in, const int* in_sizes, int n_in,
                              void* d_out, int out_size, void* d_ws, size_t ws_size,
                              hipStream_t stream) {
    const float* x    = (const float*)d_in[0];
    const float* ln_w = (const float*)d_in[1];
    const float* ln_b = (const float*)d_in[2];
    const float* wq   = (const float*)d_in[3];
    const float* wk   = (const float*)d_in[4];
    const float* wv   = (const float*)d_in[5];
    const float* wo   = (const float*)d_in[6];
    const float* wg   = (const float*)d_in[7];
    const float* wu   = (const float*)d_in[8];
    const float* wd   = (const float*)d_in[9];
    float* out = (float*)d_out;

    char* ws = (char*)d_ws;
    // workspace layout (bytes)
    u16* QKVT   = (u16*)(ws + 0x0000000);  // [1536][1024] bf16 (wq^T | wk^T | wv^T)  3MB
    u16* WOT    = (u16*)(ws + 0x0300000);  // [1024][1024] bf16                       2MB
    u16* WGT    = (u16*)(ws + 0x0500000);  // [4096][1024] bf16                       8MB
    u16* WUT    = (u16*)(ws + 0x0D00000);  // [4096][1024] bf16                       8MB
    u16* WDT    = (u16*)(ws + 0x1500000);  // [1024][4096] bf16                       8MB
    u16* NORMED = (u16*)(ws + 0x1D00000);  // [4096][1024] bf16                       8MB
    u16* G      = (u16*)(ws + 0x2500000);  // [4096][4096] bf16                      32MB
    u16* H      = (u16*)(ws + 0x4500000);  // [4096][4096] bf16                      32MB
    float* P1   = (float*)(ws + 0x6500000); // [4096][1024] f32                      16MB
    float* P2   = (float*)(ws + 0x7500000); // [4096][1024] f32                      16MB
    // attention scratch overlays G (G is dead once H is computed)
    u16* QKV  = (u16*)(ws + 0x2500000);    // [4096][1536] bf16                      12MB
    u16* VT   = (u16*)(ws + 0x3100000);    // [2][4][64][2048] bf16                   2MB
    u16* ATTN = (u16*)(ws + 0x3300000);    // [4096][1024] bf16                       8MB

    // 1. weight transposes (fp32 [K][N] -> bf16 [N][K])
    transpose_cast<<<dim3(32, 32), 256, 0, stream>>>(wq, QKVT, 1024, 1024);
    transpose_cast<<<dim3(8, 32), 256, 0, stream>>>(wk, QKVT + (size_t)1024 * 1024, 1024, 256);
    transpose_cast<<<dim3(8, 32), 256, 0, stream>>>(wv, QKVT + (size_t)1280 * 1024, 1024, 256);
    transpose_cast<<<dim3(32, 32), 256, 0, stream>>>(wo, WOT, 1024, 1024);
    transpose_cast<<<dim3(128, 32), 256, 0, stream>>>(wg, WGT, 1024, 4096);
    transpose_cast<<<dim3(128, 32), 256, 0, stream>>>(wu, WUT, 1024, 4096);
    transpose_cast<<<dim3(32, 128), 256, 0, stream>>>(wd, WDT, 4096, 1024);

    // 2. layernorm
    ln_kernel<<<4096, 256, 0, stream>>>(x, ln_w, ln_b, NORMED);

    // 3. FFN first (so attention scratch can overlay G afterwards)
    gemm_bt<<<dim3(32, 32), 256, 0, stream>>>(NORMED, WGT, G, nullptr, 4096, 1024, 0);
    gemm_bt<<<dim3(32, 32), 256, 0, stream>>>(NORMED, WUT, H, G, 4096, 1024, 2);
    gemm_bt<<<dim3(32, 8), 256, 0, stream>>>(H, WDT, P2, nullptr, 1024, 4096, 1);

    // 4. fused QKV projection
    gemm_bt<<<dim3(32, 12), 256, 0, stream>>>(NORMED, QKVT, QKV, nullptr, 1536, 1024, 0);

    // 5. V transpose: qkv cols 1280..1535 -> VT [b][kh][d][s]
    transpose_v<<<dim3(8, 64, 2), 256, 0, stream>>>(QKV + 1280, VT, 1536);

    // 6. attention
    attn_kernel<<<1024, 256, 0, stream>>>(QKV, VT, ATTN);

    // 7. output projection
    gemm_bt<<<dim3(32, 8), 256, 0, stream>>>(ATTN, WOT, P1, nullptr, 1024, 1024, 1);

    // 8. residual add
    add3_kernel<<<4096, 256, 0, stream>>>(x, P1, P2, out);
}